// Round 2
// baseline (2003.268 us; speedup 1.0000x reference)
//
#include <hip/hip_runtime.h>
#include <hip/hip_bf16.h>

// Problem constants
#define B_   256
#define L_   512
#define D_   768
#define H_   1000   // ATTN_H
#define XDIM 2324   // 2*D + D + 20
#define MAXPOS (B_*L_)   // 131072

// ---------------------------------------------------------------------------
// Kernel 1: per-batch width scan (1 block). meta layout:
//   meta[0..255]   = exclusive offset per batch
//   meta[256..511] = start per batch
//   meta[512..767] = end per batch
//   meta[768]      = total npos
// NOTE: spans arrive as int32 (harness downcasts int64 inputs to int).
__global__ __launch_bounds__(256) void scan_kernel(const int* __restrict__ spans,
                                                   int* __restrict__ meta) {
    int b = threadIdx.x;
    int s = spans[2 * b], e = spans[2 * b + 1];
    // defensive clamps — a bad span must never fault downstream kernels
    s = min(max(s, 0), L_ - 1);
    e = min(max(e, s), L_ - 1);
    int w = e - s + 1;                 // 1..512
    __shared__ int sw[256];
    sw[b] = w;
    __syncthreads();
    for (int d = 1; d < 256; d <<= 1) {
        int v = 0;
        if (b >= d) v = sw[b - d];
        __syncthreads();
        if (b >= d) sw[b] += v;
        __syncthreads();
    }
    meta[b]       = sw[b] - w;      // exclusive prefix
    meta[256 + b] = s;
    meta[512 + b] = e;
    if (b == 255) meta[768] = sw[255];
}

// Kernel 2: fill compacted (b,l) position list
__global__ __launch_bounds__(256) void pos_fill(const int* __restrict__ meta,
                                                int* __restrict__ pos_list) {
    int b = blockIdx.x;
    int off = meta[b], start = meta[256 + b], end = meta[512 + b];
    int w = end - start + 1;
    for (int i = threadIdx.x; i < w; i += blockDim.x)
        pos_list[off + i] = (b << 16) | (start + i);
}

// ---------------------------------------------------------------------------
// Kernel 3: the big fused GEMM.
// attns[row] = sum_j leaky(E[row]·aw1[:,j] + ab1[j]) * aw2[j]
// Tiled: BM=64 rows x BN=128 hidden, K=768, atomicAdd partials per j-tile.
#define BM 64
#define BN 128
#define KT 16
__global__ __launch_bounds__(256) void attn_gemm(
    const float* __restrict__ embeds, const float* __restrict__ aw1,
    const float* __restrict__ ab1, const float* __restrict__ aw2,
    const int* __restrict__ pos_list, const int* __restrict__ meta,
    float* __restrict__ attns) {
    int npos = meta[768];
    int m0 = blockIdx.x * BM;
    if (m0 >= npos) return;
    int j0 = blockIdx.y * BN;
    int t = threadIdx.x;
    int tx = t & 15, ty = t >> 4;

    __shared__ float Es[KT][BM + 4];   // transposed E tile, padded (row = 272B, 16B-aligned)
    __shared__ float Ws[KT][BN];

    // E-load mapping: 4 threads/row, float4 each
    int lr = t >> 2;            // 0..63
    int lc = (t & 3) * 4;       // 0,4,8,12
    const float* erow = nullptr;
    int m = m0 + lr;
    if (m < npos) {
        int p = pos_list[m];
        int bb = p >> 16, ll = p & 0xffff;
        erow = embeds + ((size_t)bb * L_ + ll) * D_;
    }
    // W-load mapping: rows wk, wk+8; float4 cols
    int wk = t >> 5;            // 0..7
    int wc = (t & 31) * 4;      // 0..124

    float acc[4][8];
#pragma unroll
    for (int i = 0; i < 4; i++)
#pragma unroll
        for (int j = 0; j < 8; j++) acc[i][j] = 0.f;

    for (int k0 = 0; k0 < D_; k0 += KT) {
        float4 ev = make_float4(0.f, 0.f, 0.f, 0.f);
        if (erow) ev = *(const float4*)(erow + k0 + lc);
        Es[lc + 0][lr] = ev.x;
        Es[lc + 1][lr] = ev.y;
        Es[lc + 2][lr] = ev.z;
        Es[lc + 3][lr] = ev.w;
#pragma unroll
        for (int h = 0; h < 2; h++) {
            int kk = wk + h * 8;
            int col = j0 + wc;
            float4 wv;
            if (col + 3 < H_) {
                wv = *(const float4*)(aw1 + (size_t)(k0 + kk) * H_ + col);
            } else {
                float tmp[4];
#pragma unroll
                for (int q = 0; q < 4; q++)
                    tmp[q] = (col + q < H_) ? aw1[(size_t)(k0 + kk) * H_ + col + q] : 0.f;
                wv = make_float4(tmp[0], tmp[1], tmp[2], tmp[3]);
            }
            *(float4*)&Ws[kk][wc] = wv;
        }
        __syncthreads();
#pragma unroll
        for (int kk = 0; kk < KT; kk++) {
            float4 a  = *(const float4*)&Es[kk][ty * 4];
            float4 b0 = *(const float4*)&Ws[kk][tx * 8];
            float4 b1 = *(const float4*)&Ws[kk][tx * 8 + 4];
            float av[4] = {a.x, a.y, a.z, a.w};
            float bv[8] = {b0.x, b0.y, b0.z, b0.w, b1.x, b1.y, b1.z, b1.w};
#pragma unroll
            for (int i = 0; i < 4; i++)
#pragma unroll
                for (int j = 0; j < 8; j++) acc[i][j] += av[i] * bv[j];
        }
        __syncthreads();
    }

    // epilogue: leaky + aw2 dot, reduce across the 16 tx lanes, atomicAdd
    float a2[8], bb1[8];
#pragma unroll
    for (int j = 0; j < 8; j++) {
        int col = j0 + tx * 8 + j;
        a2[j]  = (col < H_) ? aw2[col] : 0.f;
        bb1[j] = (col < H_) ? ab1[col] : 0.f;
    }
#pragma unroll
    for (int i = 0; i < 4; i++) {
        float p = 0.f;
#pragma unroll
        for (int j = 0; j < 8; j++) {
            float h = acc[i][j] + bb1[j];
            h = h > 0.f ? h : 0.01f * h;
            p += h * a2[j];
        }
        p += __shfl_xor(p, 1);
        p += __shfl_xor(p, 2);
        p += __shfl_xor(p, 4);
        p += __shfl_xor(p, 8);
        int row = m0 + ty * 4 + i;
        if (tx == 0 && row < npos) atomicAdd(&attns[row], p);
    }
}

// ---------------------------------------------------------------------------
// Kernel 4: per-batch softmax over span + weighted embed sum + se + width emb
// builds x[b, 0:2324] = [emb[start], emb[end], attn_embeds, wemb]
__global__ __launch_bounds__(256) void build_x(
    const float* __restrict__ embeds, const float* __restrict__ attns,
    const int* __restrict__ meta, const float* __restrict__ width_emb,
    float* __restrict__ x) {
    int b = blockIdx.x, t = threadIdx.x;
    int off = meta[b], start = meta[256 + b], end = meta[512 + b];
    int w = end - start + 1;
    __shared__ float sv[512];
    __shared__ float red[256];
    for (int i = t; i < w; i += 256) sv[i] = attns[off + i];
    __syncthreads();
    float m = -3.0e38f;
    for (int i = t; i < w; i += 256) m = fmaxf(m, sv[i]);
    red[t] = m;
    __syncthreads();
    for (int s = 128; s > 0; s >>= 1) {
        if (t < s) red[t] = fmaxf(red[t], red[t + s]);
        __syncthreads();
    }
    float mx = red[0];
    __syncthreads();
    float ssum = 0.f;
    for (int i = t; i < w; i += 256) {
        float e = expf(sv[i] - mx);
        sv[i] = e;
        ssum += e;
    }
    red[t] = ssum;
    __syncthreads();
    for (int s = 128; s > 0; s >>= 1) {
        if (t < s) red[t] += red[t + s];
        __syncthreads();
    }
    float inv = 1.0f / red[0];
    __syncthreads();

    float acc0 = 0.f, acc1 = 0.f, acc2 = 0.f;
    const float* base = embeds + ((size_t)b * L_ + start) * D_;
    for (int i = 0; i < w; i++) {
        float wi = sv[i] * inv;
        const float* row = base + (size_t)i * D_;
        acc0 += wi * row[t];
        acc1 += wi * row[t + 256];
        acc2 += wi * row[t + 512];
    }
    float* xb = x + (size_t)b * XDIM;
    xb[1536 + t]       = acc0;
    xb[1536 + 256 + t] = acc1;
    xb[1536 + 512 + t] = acc2;
    const float* re = embeds + ((size_t)b * L_ + end) * D_;
    xb[t]        = base[t];
    xb[256 + t]  = base[t + 256];
    xb[512 + t]  = base[t + 512];
    xb[768 + t]  = re[t];
    xb[1024 + t] = re[t + 256];
    xb[1280 + t] = re[t + 512];
    if (t < 20) {
        const int bins[15] = {1, 2, 3, 4, 5, 6, 7, 8, 12, 16, 20, 24, 32, 64, 128};
        int idx = 0;
#pragma unroll
        for (int q = 0; q < 15; q++) idx += (w > bins[q]);
        xb[2304 + t] = width_emb[idx * 20 + t];
    }
}

// ---------------------------------------------------------------------------
// Kernel 5: generic tiled SGEMM, out = [leaky](A@W + bias). BM=BN=64, KT=8.
template <int APPLY_LEAKY>
__global__ __launch_bounds__(256) void mlp_gemm(
    const float* __restrict__ A, const float* __restrict__ W,
    const float* __restrict__ bias, float* __restrict__ out,
    int M, int N, int K) {
    __shared__ float As[8][68];
    __shared__ float Ws[8][64];
    int t = threadIdx.x;
    int tx = t & 15, ty = t >> 4;
    int m0 = blockIdx.x * 64, n0 = blockIdx.y * 64;
    int lr = t >> 2, lc = (t & 3) * 2;
    int wk = t >> 5, wc = (t & 31) * 2;
    float acc[4][4] = {{0.f}};
    for (int k0 = 0; k0 < K; k0 += 8) {
        float a0 = 0.f, a1 = 0.f;
        if (m0 + lr < M) {
            if (k0 + lc + 1 < K) {
                float2 v = *(const float2*)(A + (size_t)(m0 + lr) * K + k0 + lc);
                a0 = v.x; a1 = v.y;
            } else if (k0 + lc < K) {
                a0 = A[(size_t)(m0 + lr) * K + k0 + lc];
            }
        }
        As[lc][lr] = a0;
        As[lc + 1][lr] = a1;
        float w0 = 0.f, w1 = 0.f;
        if (k0 + wk < K) {
            int col = n0 + wc;
            if (col + 1 < N) {
                float2 v = *(const float2*)(W + (size_t)(k0 + wk) * N + col);
                w0 = v.x; w1 = v.y;
            } else if (col < N) {
                w0 = W[(size_t)(k0 + wk) * N + col];
            }
        }
        Ws[wk][wc] = w0;
        Ws[wk][wc + 1] = w1;
        __syncthreads();
#pragma unroll
        for (int kk = 0; kk < 8; kk++) {
            float4 a = *(const float4*)&As[kk][ty * 4];
            float4 b = *(const float4*)&Ws[kk][tx * 4];
            float av[4] = {a.x, a.y, a.z, a.w};
            float bv[4] = {b.x, b.y, b.z, b.w};
#pragma unroll
            for (int i = 0; i < 4; i++)
#pragma unroll
                for (int j = 0; j < 4; j++) acc[i][j] += av[i] * bv[j];
        }
        __syncthreads();
    }
#pragma unroll
    for (int i = 0; i < 4; i++) {
#pragma unroll
        for (int j = 0; j < 4; j++) {
            int mm = m0 + ty * 4 + i, nn = n0 + tx * 4 + j;
            if (mm < M && nn < N) {
                float v = acc[i][j] + bias[nn];
                if (APPLY_LEAKY) v = v > 0.f ? v : 0.01f * v;
                out[(size_t)mm * N + nn] = v;
            }
        }
    }
}

// ---------------------------------------------------------------------------
extern "C" void kernel_launch(void* const* d_in, const int* in_sizes, int n_in,
                              void* d_out, int out_size, void* d_ws, size_t ws_size,
                              hipStream_t stream) {
    const float* embeds    = (const float*)d_in[0];
    const int*   spans     = (const int*)d_in[1];   // int64 in ref -> int32 on device
    const float* aw1       = (const float*)d_in[2];
    const float* ab1       = (const float*)d_in[3];
    const float* aw2       = (const float*)d_in[4];
    // d_in[5] = ab2: softmax is shift-invariant within the mask -> unused
    const float* width_emb = (const float*)d_in[6];
    const float* sw1 = (const float*)d_in[7],  *sb1 = (const float*)d_in[8];
    const float* sw2 = (const float*)d_in[9],  *sb2 = (const float*)d_in[10];
    const float* sw3 = (const float*)d_in[11], *sb3 = (const float*)d_in[12];
    const float* sw4 = (const float*)d_in[13], *sb4 = (const float*)d_in[14];
    float* out = (float*)d_out;

    char* ws = (char*)d_ws;
    float* attns    = (float*)ws;                          // MAXPOS floats
    int*   pos_list = (int*)(ws + (size_t)MAXPOS * 4);     // MAXPOS ints
    int*   meta     = (int*)(ws + (size_t)MAXPOS * 8);     // 1024 ints
    float* x  = (float*)(ws + (size_t)MAXPOS * 8 + 4096);  // 256*2324
    float* y1 = x + (size_t)B_ * XDIM;                     // 256*1024
    float* y2 = y1 + (size_t)B_ * 1024;                    // 256*512
    float* y3 = y2 + (size_t)B_ * 512;                     // 256*256

    hipMemsetAsync(attns, 0, (size_t)MAXPOS * 4, stream);
    scan_kernel<<<1, 256, 0, stream>>>(spans, meta);
    pos_fill<<<B_, 256, 0, stream>>>(meta, pos_list);
    attn_gemm<<<dim3(MAXPOS / BM, (H_ + BN - 1) / BN), 256, 0, stream>>>(
        embeds, aw1, ab1, aw2, pos_list, meta, attns);
    build_x<<<B_, 256, 0, stream>>>(embeds, attns, meta, width_emb, x);
    mlp_gemm<1><<<dim3(4, 16), 256, 0, stream>>>(x,  sw1, sb1, y1, B_, 1024, XDIM);
    mlp_gemm<1><<<dim3(4, 8),  256, 0, stream>>>(y1, sw2, sb2, y2, B_, 512, 1024);
    mlp_gemm<1><<<dim3(4, 4),  256, 0, stream>>>(y2, sw3, sb3, y3, B_, 256, 512);
    mlp_gemm<0><<<dim3(4, 1),  256, 0, stream>>>(y3, sw4, sb4, out, B_, 30, 256);
}

// Round 4
// 1358.650 us; speedup vs baseline: 1.4745x; 1.4745x over previous
//
#include <hip/hip_runtime.h>
#include <hip/hip_bf16.h>

// Problem constants
#define B_   256
#define L_   512
#define D_   768
#define H_   1000   // ATTN_H
#define NPAD 1024   // H_ padded to MFMA tile
#define XDIM 2324   // 2*D + D + 20
#define MAXPOS (B_*L_)   // 131072

typedef _Float16 half8 __attribute__((ext_vector_type(8)));
typedef float    f32x4 __attribute__((ext_vector_type(4)));

// ---------------------------------------------------------------------------
// Kernel 1: per-batch width scan (1 block). meta layout:
//   meta[0..255] offs | meta[256..511] start | meta[512..767] end | meta[768] npos
__global__ __launch_bounds__(256) void scan_kernel(const int* __restrict__ spans,
                                                   int* __restrict__ meta) {
    int b = threadIdx.x;
    int s = spans[2 * b], e = spans[2 * b + 1];
    s = min(max(s, 0), L_ - 1);
    e = min(max(e, s), L_ - 1);
    int w = e - s + 1;
    __shared__ int sw[256];
    sw[b] = w;
    __syncthreads();
    for (int d = 1; d < 256; d <<= 1) {
        int v = 0;
        if (b >= d) v = sw[b - d];
        __syncthreads();
        if (b >= d) sw[b] += v;
        __syncthreads();
    }
    meta[b]       = sw[b] - w;
    meta[256 + b] = s;
    meta[512 + b] = e;
    if (b == 255) meta[768] = sw[255];
}

// Kernel 2: compacted (b,l) position list
__global__ __launch_bounds__(256) void pos_fill(const int* __restrict__ meta,
                                                int* __restrict__ pos_list) {
    int b = blockIdx.x;
    int off = meta[b], start = meta[256 + b], end = meta[512 + b];
    int w = end - start + 1;
    for (int i = threadIdx.x; i < w; i += blockDim.x)
        pos_list[off + i] = (b << 16) | (start + i);
}

// ---------------------------------------------------------------------------
// Kernel 3: aw1 [768][1000] fp32 -> WbT [1024][768] f16 (transposed, zero-pad)
__global__ __launch_bounds__(256) void transpose_w(const float* __restrict__ aw1,
                                                   _Float16* __restrict__ WbT) {
    int k0 = blockIdx.x * 32, n0 = blockIdx.y * 32;
    int tx = threadIdx.x & 31, ty = threadIdx.x >> 5;   // 32 x 8
    __shared__ float T[32][33];
#pragma unroll
    for (int it = 0; it < 4; it++) {
        int k = k0 + ty + 8 * it;
        int n = n0 + tx;
        T[ty + 8 * it][tx] = (n < H_) ? aw1[(size_t)k * H_ + n] : 0.f;
    }
    __syncthreads();
#pragma unroll
    for (int it = 0; it < 4; it++) {
        int n = n0 + ty + 8 * it;
        WbT[(size_t)n * D_ + k0 + tx] = (_Float16)T[tx][ty + 8 * it];
    }
}

// ---------------------------------------------------------------------------
// Kernel 4: barrier-free MFMA GEMM + fused leaky/aw2-dot epilogue.
// Block = 32 rows (A resident in LDS, staged once). 4 waves; wave w owns cols
// [w*256, w*256+256) in 4 groups of 64. B frags load straight from L2 (WbT).
// K-loop has NO barriers: 2 ds_read_b128 + 4 global_dwordx4 + 8 MFMA per k0.
#define AP 776   // 768 + 8 pad: row stride 1552B -> b128 reads tile banks evenly
__global__ __launch_bounds__(256) void attn_gemm_v2(
    const float* __restrict__ embeds, const _Float16* __restrict__ WbT,
    const float* __restrict__ ab1, const float* __restrict__ aw2,
    const int* __restrict__ pos_list, const int* __restrict__ meta,
    float* __restrict__ attns) {
    int npos = meta[768];
    int m0 = blockIdx.x * 32;
    if (m0 >= npos) return;
    int t = threadIdx.x;
    int lane = t & 63, w = t >> 6;
    int q = lane >> 4, l15 = lane & 15;

    __shared__ alignas(16) _Float16 As[32][AP];
    __shared__ unsigned rowoff[32];
    __shared__ float attns_s[4][32];

    if (t < 32) {
        unsigned off = 0;
        int m = m0 + t;
        if (m < npos) {
            int p = pos_list[m];
            off = (unsigned)((p >> 16) * (L_ * D_) + (p & 0xffff) * D_);
        }
        rowoff[t] = off;
    }
    __syncthreads();

    // Stage A: thread t -> row t>>3, 96 floats at col (t&7)*96, fp32->f16
    {
        int row = t >> 3;
        int cs = (t & 7) * 96;
        const float* src = embeds + rowoff[row] + cs;
#pragma unroll
        for (int i2 = 0; i2 < 12; i2++) {
            float4 v0 = *(const float4*)(src + i2 * 8);
            float4 v1 = *(const float4*)(src + i2 * 8 + 4);
            half8 h;
            h[0] = (_Float16)v0.x; h[1] = (_Float16)v0.y;
            h[2] = (_Float16)v0.z; h[3] = (_Float16)v0.w;
            h[4] = (_Float16)v1.x; h[5] = (_Float16)v1.y;
            h[6] = (_Float16)v1.z; h[7] = (_Float16)v1.w;
            *(half8*)&As[row][cs + i2 * 8] = h;
        }
    }
    __syncthreads();

    float pacc[2][4];
#pragma unroll
    for (int i = 0; i < 2; i++)
#pragma unroll
        for (int r = 0; r < 4; r++) pacc[i][r] = 0.f;

    for (int g = 0; g < 4; g++) {
        int colbase = w * 256 + g * 64;
        const _Float16* bbase = WbT + (size_t)(colbase + l15) * D_ + q * 8;
        f32x4 acc[2][4];
#pragma unroll
        for (int i = 0; i < 2; i++)
#pragma unroll
            for (int j = 0; j < 4; j++) acc[i][j] = (f32x4){0.f, 0.f, 0.f, 0.f};

        for (int k0 = 0; k0 < D_; k0 += 32) {
            half8 bf[4];
#pragma unroll
            for (int j = 0; j < 4; j++)
                bf[j] = *(const half8*)(bbase + (size_t)j * 16 * D_ + k0);
            half8 af[2];
#pragma unroll
            for (int i = 0; i < 2; i++)
                af[i] = *(const half8*)&As[l15 + 16 * i][k0 + q * 8];
#pragma unroll
            for (int i = 0; i < 2; i++)
#pragma unroll
                for (int j = 0; j < 4; j++)
                    acc[i][j] = __builtin_amdgcn_mfma_f32_16x16x32_f16(af[i], bf[j], acc[i][j], 0, 0, 0);
        }

        // epilogue for this 64-col group
        float bj[4], aj[4];
#pragma unroll
        for (int j = 0; j < 4; j++) {
            int col = colbase + j * 16 + l15;
            bool v = col < H_;
            bj[j] = v ? ab1[col] : 0.f;
            aj[j] = v ? aw2[col] : 0.f;
        }
#pragma unroll
        for (int i = 0; i < 2; i++) {
#pragma unroll
            for (int r = 0; r < 4; r++) {
                float p = 0.f;
#pragma unroll
                for (int j = 0; j < 4; j++) {
                    float h = acc[i][j][r] + bj[j];
                    h = h > 0.f ? h : 0.01f * h;
                    p += h * aj[j];
                }
                p += __shfl_xor(p, 1);
                p += __shfl_xor(p, 2);
                p += __shfl_xor(p, 4);
                p += __shfl_xor(p, 8);
                pacc[i][r] += p;   // valid at l15==0
            }
        }
    }
    if (l15 == 0) {
#pragma unroll
        for (int i = 0; i < 2; i++)
#pragma unroll
            for (int r = 0; r < 4; r++)
                attns_s[w][i * 16 + q * 4 + r] = pacc[i][r];
    }
    __syncthreads();
    if (t < 32 && m0 + t < npos)
        attns[m0 + t] = attns_s[0][t] + attns_s[1][t] + attns_s[2][t] + attns_s[3][t];
}

// ---------------------------------------------------------------------------
// Kernel 5: softmax + weighted sum, 3 dim-slices per batch.
__global__ __launch_bounds__(256) void build_x(
    const float* __restrict__ embeds, const float* __restrict__ attns,
    const int* __restrict__ meta, const float* __restrict__ width_emb,
    float* __restrict__ x) {
    int b = blockIdx.x, s = blockIdx.y, t = threadIdx.x;
    int off = meta[b], start = meta[256 + b], end = meta[512 + b];
    int w = end - start + 1;
    __shared__ float sv[512];
    __shared__ float red[256];
    for (int i = t; i < w; i += 256) sv[i] = attns[off + i];
    __syncthreads();
    float m = -3.0e38f;
    for (int i = t; i < w; i += 256) m = fmaxf(m, sv[i]);
    red[t] = m;
    __syncthreads();
    for (int st = 128; st > 0; st >>= 1) {
        if (t < st) red[t] = fmaxf(red[t], red[t + st]);
        __syncthreads();
    }
    float mx = red[0];
    __syncthreads();
    float ssum = 0.f;
    for (int i = t; i < w; i += 256) {
        float e = __expf(sv[i] - mx);
        sv[i] = e;
        ssum += e;
    }
    red[t] = ssum;
    __syncthreads();
    for (int st = 128; st > 0; st >>= 1) {
        if (t < st) red[t] += red[t + st];
        __syncthreads();
    }
    float inv = 1.0f / red[0];
    __syncthreads();

    int dim = s * 256 + t;
    const float* base = embeds + ((size_t)b * L_ + start) * D_ + dim;
    float acc = 0.f;
    int i = 0;
    for (; i + 3 < w; i += 4) {
        float w0 = sv[i], w1 = sv[i + 1], w2 = sv[i + 2], w3 = sv[i + 3];
        const float* p = base + (size_t)i * D_;
        acc += w0 * p[0] + w1 * p[D_] + w2 * p[2 * D_] + w3 * p[3 * D_];
    }
    for (; i < w; i++) acc += sv[i] * base[(size_t)i * D_];

    float* xb = x + (size_t)b * XDIM;
    xb[1536 + dim] = acc * inv;
    xb[dim]        = base[0];
    xb[768 + dim]  = embeds[((size_t)b * L_ + end) * D_ + dim];
    if (s == 0 && t < 20) {
        const int bins[15] = {1, 2, 3, 4, 5, 6, 7, 8, 12, 16, 20, 24, 32, 64, 128};
        int idx = 0;
#pragma unroll
        for (int q2 = 0; q2 < 15; q2++) idx += (w > bins[q2]);
        xb[2304 + t] = width_emb[idx * 20 + t];
    }
}

// ---------------------------------------------------------------------------
// Kernel 6: generic tiled SGEMM, out = [leaky](A@W + bias). fp32. (R2-validated)
template <int APPLY_LEAKY>
__global__ __launch_bounds__(256) void mlp_gemm(
    const float* __restrict__ A, const float* __restrict__ W,
    const float* __restrict__ bias, float* __restrict__ out,
    int M, int N, int K) {
    __shared__ float As[8][68];
    __shared__ float Ws[8][64];
    int t = threadIdx.x;
    int tx = t & 15, ty = t >> 4;
    int m0 = blockIdx.x * 64, n0 = blockIdx.y * 64;
    int lr = t >> 2, lc = (t & 3) * 2;
    int wk = t >> 5, wc = (t & 31) * 2;
    float acc[4][4] = {{0.f}};
    for (int k0 = 0; k0 < K; k0 += 8) {
        float a0 = 0.f, a1 = 0.f;
        if (m0 + lr < M) {
            if (k0 + lc + 1 < K) {
                float2 v = *(const float2*)(A + (size_t)(m0 + lr) * K + k0 + lc);
                a0 = v.x; a1 = v.y;
            } else if (k0 + lc < K) {
                a0 = A[(size_t)(m0 + lr) * K + k0 + lc];
            }
        }
        As[lc][lr] = a0;
        As[lc + 1][lr] = a1;
        float w0 = 0.f, w1 = 0.f;
        if (k0 + wk < K) {
            int col = n0 + wc;
            if (col + 1 < N) {
                float2 v = *(const float2*)(W + (size_t)(k0 + wk) * N + col);
                w0 = v.x; w1 = v.y;
            } else if (col < N) {
                w0 = W[(size_t)(k0 + wk) * N + col];
            }
        }
        Ws[wk][wc] = w0;
        Ws[wk][wc + 1] = w1;
        __syncthreads();
#pragma unroll
        for (int kk = 0; kk < 8; kk++) {
            float4 a = *(const float4*)&As[kk][ty * 4];
            float4 b = *(const float4*)&Ws[kk][tx * 4];
            float av[4] = {a.x, a.y, a.z, a.w};
            float bv[4] = {b.x, b.y, b.z, b.w};
#pragma unroll
            for (int i = 0; i < 4; i++)
#pragma unroll
                for (int j = 0; j < 4; j++) acc[i][j] += av[i] * bv[j];
        }
        __syncthreads();
    }
#pragma unroll
    for (int i = 0; i < 4; i++) {
#pragma unroll
        for (int j = 0; j < 4; j++) {
            int mm = m0 + ty * 4 + i, nn = n0 + tx * 4 + j;
            if (mm < M && nn < N) {
                float v = acc[i][j] + bias[nn];
                if (APPLY_LEAKY) v = v > 0.f ? v : 0.01f * v;
                out[(size_t)mm * N + nn] = v;
            }
        }
    }
}

// ---------------------------------------------------------------------------
extern "C" void kernel_launch(void* const* d_in, const int* in_sizes, int n_in,
                              void* d_out, int out_size, void* d_ws, size_t ws_size,
                              hipStream_t stream) {
    const float* embeds    = (const float*)d_in[0];
    const int*   spans     = (const int*)d_in[1];   // int64 ref -> int32 device
    const float* aw1       = (const float*)d_in[2];
    const float* ab1       = (const float*)d_in[3];
    const float* aw2       = (const float*)d_in[4];
    // d_in[5] = ab2: softmax shift-invariant -> unused
    const float* width_emb = (const float*)d_in[6];
    const float* sw1 = (const float*)d_in[7],  *sb1 = (const float*)d_in[8];
    const float* sw2 = (const float*)d_in[9],  *sb2 = (const float*)d_in[10];
    const float* sw3 = (const float*)d_in[11], *sb3 = (const float*)d_in[12];
    const float* sw4 = (const float*)d_in[13], *sb4 = (const float*)d_in[14];
    float* out = (float*)d_out;

    char* ws = (char*)d_ws;
    float*     attns    = (float*)ws;                              // 512 KB
    int*       pos_list = (int*)(ws + (size_t)MAXPOS * 4);         // 512 KB
    int*       meta     = (int*)(ws + (size_t)MAXPOS * 8);         // 4 KB
    _Float16*  WbT      = (_Float16*)(ws + (size_t)MAXPOS * 8 + 4096);  // 1.5 MB
    float* x  = (float*)(ws + (size_t)MAXPOS * 8 + 4096 + (size_t)NPAD * D_ * 2);
    float* y1 = x + (size_t)B_ * XDIM;
    float* y2 = y1 + (size_t)B_ * 1024;
    float* y3 = y2 + (size_t)B_ * 512;

    scan_kernel<<<1, 256, 0, stream>>>(spans, meta);
    pos_fill<<<B_, 256, 0, stream>>>(meta, pos_list);
    transpose_w<<<dim3(D_ / 32, NPAD / 32), 256, 0, stream>>>(aw1, WbT);
    attn_gemm_v2<<<MAXPOS / 32, 256, 0, stream>>>(
        embeds, WbT, ab1, aw2, pos_list, meta, attns);
    build_x<<<dim3(B_, 3), 256, 0, stream>>>(embeds, attns, meta, width_emb, x);
    mlp_gemm<1><<<dim3(4, 16), 256, 0, stream>>>(x,  sw1, sb1, y1, B_, 1024, XDIM);
    mlp_gemm<1><<<dim3(4, 8),  256, 0, stream>>>(y1, sw2, sb2, y2, B_, 512, 1024);
    mlp_gemm<1><<<dim3(4, 4),  256, 0, stream>>>(y2, sw3, sb3, y3, B_, 256, 512);
    mlp_gemm<0><<<dim3(4, 1),  256, 0, stream>>>(y3, sw4, sb4, out, B_, 30, 256);
}

// Round 5
// 903.714 us; speedup vs baseline: 2.2167x; 1.5034x over previous
//
#include <hip/hip_runtime.h>
#include <hip/hip_bf16.h>

// Problem constants
#define B_   256
#define L_   512
#define D_   768
#define H_   1000   // ATTN_H
#define NPAD 1024   // H_ padded to MFMA tile
#define XDIM 2324   // 2*D + D + 20
#define MAXPOS (B_*L_)   // 131072

typedef _Float16 half8 __attribute__((ext_vector_type(8)));
typedef float    f32x4 __attribute__((ext_vector_type(4)));

// ---------------------------------------------------------------------------
// Kernel 1: per-batch width scan (1 block). meta layout:
//   meta[0..255] offs | meta[256..511] start | meta[512..767] end | meta[768] npos
__global__ __launch_bounds__(256) void scan_kernel(const int* __restrict__ spans,
                                                   int* __restrict__ meta) {
    int b = threadIdx.x;
    int s = spans[2 * b], e = spans[2 * b + 1];
    s = min(max(s, 0), L_ - 1);
    e = min(max(e, s), L_ - 1);
    int w = e - s + 1;
    __shared__ int sw[256];
    sw[b] = w;
    __syncthreads();
    for (int d = 1; d < 256; d <<= 1) {
        int v = 0;
        if (b >= d) v = sw[b - d];
        __syncthreads();
        if (b >= d) sw[b] += v;
        __syncthreads();
    }
    meta[b]       = sw[b] - w;
    meta[256 + b] = s;
    meta[512 + b] = e;
    if (b == 255) meta[768] = sw[255];
}

// Kernel 2: compacted (b,l) position list
__global__ __launch_bounds__(256) void pos_fill(const int* __restrict__ meta,
                                                int* __restrict__ pos_list) {
    int b = blockIdx.x;
    int off = meta[b], start = meta[256 + b], end = meta[512 + b];
    int w = end - start + 1;
    for (int i = threadIdx.x; i < w; i += blockDim.x)
        pos_list[off + i] = (b << 16) | (start + i);
}

// ---------------------------------------------------------------------------
// Kernel 3: aw1 [768][1000] fp32 -> WbT [1024][768] f16 (transposed, zero-pad)
__global__ __launch_bounds__(256) void transpose_w(const float* __restrict__ aw1,
                                                   _Float16* __restrict__ WbT) {
    int k0 = blockIdx.x * 32, n0 = blockIdx.y * 32;
    int tx = threadIdx.x & 31, ty = threadIdx.x >> 5;   // 32 x 8
    __shared__ float T[32][33];
#pragma unroll
    for (int it = 0; it < 4; it++) {
        int k = k0 + ty + 8 * it;
        int n = n0 + tx;
        T[ty + 8 * it][tx] = (n < H_) ? aw1[(size_t)k * H_ + n] : 0.f;
    }
    __syncthreads();
#pragma unroll
    for (int it = 0; it < 4; it++) {
        int n = n0 + ty + 8 * it;
        WbT[(size_t)n * D_ + k0 + tx] = (_Float16)T[tx][ty + 8 * it];
    }
}

// ---------------------------------------------------------------------------
// Kernel 4: barrier-free MFMA GEMM + fused leaky/aw2-dot epilogue. (R4-validated)
#define AP 776   // 768 + 8 pad
__global__ __launch_bounds__(256) void attn_gemm_v2(
    const float* __restrict__ embeds, const _Float16* __restrict__ WbT,
    const float* __restrict__ ab1, const float* __restrict__ aw2,
    const int* __restrict__ pos_list, const int* __restrict__ meta,
    float* __restrict__ attns) {
    int npos = meta[768];
    int m0 = blockIdx.x * 32;
    if (m0 >= npos) return;
    int t = threadIdx.x;
    int lane = t & 63, w = t >> 6;
    int q = lane >> 4, l15 = lane & 15;

    __shared__ alignas(16) _Float16 As[32][AP];
    __shared__ unsigned rowoff[32];
    __shared__ float attns_s[4][32];

    if (t < 32) {
        unsigned off = 0;
        int m = m0 + t;
        if (m < npos) {
            int p = pos_list[m];
            off = (unsigned)((p >> 16) * (L_ * D_) + (p & 0xffff) * D_);
        }
        rowoff[t] = off;
    }
    __syncthreads();

    {
        int row = t >> 3;
        int cs = (t & 7) * 96;
        const float* src = embeds + rowoff[row] + cs;
#pragma unroll
        for (int i2 = 0; i2 < 12; i2++) {
            float4 v0 = *(const float4*)(src + i2 * 8);
            float4 v1 = *(const float4*)(src + i2 * 8 + 4);
            half8 h;
            h[0] = (_Float16)v0.x; h[1] = (_Float16)v0.y;
            h[2] = (_Float16)v0.z; h[3] = (_Float16)v0.w;
            h[4] = (_Float16)v1.x; h[5] = (_Float16)v1.y;
            h[6] = (_Float16)v1.z; h[7] = (_Float16)v1.w;
            *(half8*)&As[row][cs + i2 * 8] = h;
        }
    }
    __syncthreads();

    float pacc[2][4];
#pragma unroll
    for (int i = 0; i < 2; i++)
#pragma unroll
        for (int r = 0; r < 4; r++) pacc[i][r] = 0.f;

    for (int g = 0; g < 4; g++) {
        int colbase = w * 256 + g * 64;
        const _Float16* bbase = WbT + (size_t)(colbase + l15) * D_ + q * 8;
        f32x4 acc[2][4];
#pragma unroll
        for (int i = 0; i < 2; i++)
#pragma unroll
            for (int j = 0; j < 4; j++) acc[i][j] = (f32x4){0.f, 0.f, 0.f, 0.f};

        for (int k0 = 0; k0 < D_; k0 += 32) {
            half8 bf[4];
#pragma unroll
            for (int j = 0; j < 4; j++)
                bf[j] = *(const half8*)(bbase + (size_t)j * 16 * D_ + k0);
            half8 af[2];
#pragma unroll
            for (int i = 0; i < 2; i++)
                af[i] = *(const half8*)&As[l15 + 16 * i][k0 + q * 8];
#pragma unroll
            for (int i = 0; i < 2; i++)
#pragma unroll
                for (int j = 0; j < 4; j++)
                    acc[i][j] = __builtin_amdgcn_mfma_f32_16x16x32_f16(af[i], bf[j], acc[i][j], 0, 0, 0);
        }

        float bj[4], aj[4];
#pragma unroll
        for (int j = 0; j < 4; j++) {
            int col = colbase + j * 16 + l15;
            bool v = col < H_;
            bj[j] = v ? ab1[col] : 0.f;
            aj[j] = v ? aw2[col] : 0.f;
        }
#pragma unroll
        for (int i = 0; i < 2; i++) {
#pragma unroll
            for (int r = 0; r < 4; r++) {
                float p = 0.f;
#pragma unroll
                for (int j = 0; j < 4; j++) {
                    float h = acc[i][j][r] + bj[j];
                    h = h > 0.f ? h : 0.01f * h;
                    p += h * aj[j];
                }
                p += __shfl_xor(p, 1);
                p += __shfl_xor(p, 2);
                p += __shfl_xor(p, 4);
                p += __shfl_xor(p, 8);
                pacc[i][r] += p;
            }
        }
    }
    if (l15 == 0) {
#pragma unroll
        for (int i = 0; i < 2; i++)
#pragma unroll
            for (int r = 0; r < 4; r++)
                attns_s[w][i * 16 + q * 4 + r] = pacc[i][r];
    }
    __syncthreads();
    if (t < 32 && m0 + t < npos)
        attns[m0 + t] = attns_s[0][t] + attns_s[1][t] + attns_s[2][t] + attns_s[3][t];
}

// ---------------------------------------------------------------------------
// Kernel 5: softmax + weighted sum, 3 dim-slices per batch. (R4-validated)
__global__ __launch_bounds__(256) void build_x(
    const float* __restrict__ embeds, const float* __restrict__ attns,
    const int* __restrict__ meta, const float* __restrict__ width_emb,
    float* __restrict__ x) {
    int b = blockIdx.x, s = blockIdx.y, t = threadIdx.x;
    int off = meta[b], start = meta[256 + b], end = meta[512 + b];
    int w = end - start + 1;
    __shared__ float sv[512];
    __shared__ float red[256];
    for (int i = t; i < w; i += 256) sv[i] = attns[off + i];
    __syncthreads();
    float m = -3.0e38f;
    for (int i = t; i < w; i += 256) m = fmaxf(m, sv[i]);
    red[t] = m;
    __syncthreads();
    for (int st = 128; st > 0; st >>= 1) {
        if (t < st) red[t] = fmaxf(red[t], red[t + st]);
        __syncthreads();
    }
    float mx = red[0];
    __syncthreads();
    float ssum = 0.f;
    for (int i = t; i < w; i += 256) {
        float e = __expf(sv[i] - mx);
        sv[i] = e;
        ssum += e;
    }
    red[t] = ssum;
    __syncthreads();
    for (int st = 128; st > 0; st >>= 1) {
        if (t < st) red[t] += red[t + st];
        __syncthreads();
    }
    float inv = 1.0f / red[0];
    __syncthreads();

    int dim = s * 256 + t;
    const float* base = embeds + ((size_t)b * L_ + start) * D_ + dim;
    float acc = 0.f;
    int i = 0;
    for (; i + 3 < w; i += 4) {
        float w0 = sv[i], w1 = sv[i + 1], w2 = sv[i + 2], w3 = sv[i + 3];
        const float* p = base + (size_t)i * D_;
        acc += w0 * p[0] + w1 * p[D_] + w2 * p[2 * D_] + w3 * p[3 * D_];
    }
    for (; i < w; i++) acc += sv[i] * base[(size_t)i * D_];

    float* xb = x + (size_t)b * XDIM;
    xb[1536 + dim] = acc * inv;
    xb[dim]        = base[0];
    xb[768 + dim]  = embeds[((size_t)b * L_ + end) * D_ + dim];
    if (s == 0 && t < 20) {
        const int bins[15] = {1, 2, 3, 4, 5, 6, 7, 8, 12, 16, 20, 24, 32, 64, 128};
        int idx = 0;
#pragma unroll
        for (int q2 = 0; q2 < 15; q2++) idx += (w > bins[q2]);
        xb[2304 + t] = width_emb[idx * 20 + t];
    }
}

// ---------------------------------------------------------------------------
// Kernel 6: split-K fp32 GEMM. Block = 64x64 output tile x K-chunk.
// Partials atomicAdd'ed into zeroed out buffer. KT=16, double-buffered staging.
__global__ __launch_bounds__(256) void mlp_gemm_sk(
    const float* __restrict__ A, const float* __restrict__ W,
    float* __restrict__ out, int M, int N, int K, int kchunk) {
    __shared__ float As[16][68];   // As[k][m], padded
    __shared__ float Ws[16][64];   // Ws[k][n]
    int t = threadIdx.x;
    int tx = t & 15, ty = t >> 4;
    int m0 = blockIdx.x * 64, n0 = blockIdx.y * 64;
    int ks = blockIdx.z * kchunk;
    int ke = min(ks + kchunk, K);
    if (ks >= ke) return;
    int ar = t >> 2, akc = (t & 3) * 4;     // A: row ar, 4 k's
    int wk = t >> 4, wnc = (t & 15) * 4;    // W: k wk, 4 n's
    bool n4 = ((N & 3) == 0);

    float acc[4][4];
#pragma unroll
    for (int i = 0; i < 4; i++)
#pragma unroll
        for (int j = 0; j < 4; j++) acc[i][j] = 0.f;

    auto loadA = [&](int k0) -> float4 {
        float4 r = make_float4(0.f, 0.f, 0.f, 0.f);
        int k = k0 + akc;                    // akc, ke multiples of 4
        if (k < ke) r = *(const float4*)(A + (size_t)(m0 + ar) * K + k);
        return r;
    };
    auto loadW = [&](int k0) -> float4 {
        float4 r = make_float4(0.f, 0.f, 0.f, 0.f);
        int k = k0 + wk;
        if (k < ke) {
            int n = n0 + wnc;
            const float* p = W + (size_t)k * N + n;
            if (n4) {
                r = *(const float4*)p;       // full tiles when N%4==0 (N>=64 cases)
            } else {
                float tmp[4];
#pragma unroll
                for (int q2 = 0; q2 < 4; q2++)
                    tmp[q2] = (n + q2 < N) ? p[q2] : 0.f;
                r = make_float4(tmp[0], tmp[1], tmp[2], tmp[3]);
            }
        }
        return r;
    };

    float4 aR = loadA(ks), wR = loadW(ks);
    for (int k0 = ks; k0 < ke; k0 += 16) {
        As[akc + 0][ar] = aR.x;
        As[akc + 1][ar] = aR.y;
        As[akc + 2][ar] = aR.z;
        As[akc + 3][ar] = aR.w;
        *(float4*)&Ws[wk][wnc] = wR;
        __syncthreads();
        if (k0 + 16 < ke) { aR = loadA(k0 + 16); wR = loadW(k0 + 16); }
#pragma unroll
        for (int kk = 0; kk < 16; kk++) {
            float4 a = *(const float4*)&As[kk][ty * 4];
            float4 b = *(const float4*)&Ws[kk][tx * 4];
            float av[4] = {a.x, a.y, a.z, a.w};
            float bv[4] = {b.x, b.y, b.z, b.w};
#pragma unroll
            for (int i = 0; i < 4; i++)
#pragma unroll
                for (int j = 0; j < 4; j++) acc[i][j] += av[i] * bv[j];
        }
        __syncthreads();
    }
#pragma unroll
    for (int i = 0; i < 4; i++) {
#pragma unroll
        for (int j = 0; j < 4; j++) {
            int nn = n0 + tx * 4 + j;
            if (nn < N)
                atomicAdd(&out[(size_t)(m0 + ty * 4 + i) * N + nn], acc[i][j]);
        }
    }
}

// Kernel 7: elementwise bias (+ optional leaky), src -> dst
__global__ __launch_bounds__(256) void bias_act(
    const float* __restrict__ src, const float* __restrict__ bias,
    float* __restrict__ dst, int total, int N, int leaky) {
    int i = blockIdx.x * 256 + threadIdx.x;
    int stride = gridDim.x * 256;
    for (; i < total; i += stride) {
        float v = src[i] + bias[i % N];
        if (leaky) v = v > 0.f ? v : 0.01f * v;
        dst[i] = v;
    }
}

// ---------------------------------------------------------------------------
extern "C" void kernel_launch(void* const* d_in, const int* in_sizes, int n_in,
                              void* d_out, int out_size, void* d_ws, size_t ws_size,
                              hipStream_t stream) {
    const float* embeds    = (const float*)d_in[0];
    const int*   spans     = (const int*)d_in[1];   // int64 ref -> int32 device
    const float* aw1       = (const float*)d_in[2];
    const float* ab1       = (const float*)d_in[3];
    const float* aw2       = (const float*)d_in[4];
    // d_in[5] = ab2: softmax shift-invariant -> unused
    const float* width_emb = (const float*)d_in[6];
    const float* sw1 = (const float*)d_in[7],  *sb1 = (const float*)d_in[8];
    const float* sw2 = (const float*)d_in[9],  *sb2 = (const float*)d_in[10];
    const float* sw3 = (const float*)d_in[11], *sb3 = (const float*)d_in[12];
    const float* sw4 = (const float*)d_in[13], *sb4 = (const float*)d_in[14];
    float* out = (float*)d_out;

    char* ws = (char*)d_ws;
    float*     attns    = (float*)ws;                              // 512 KB
    int*       pos_list = (int*)(ws + (size_t)MAXPOS * 4);         // 512 KB
    int*       meta     = (int*)(ws + (size_t)MAXPOS * 8);         // 4 KB
    _Float16*  WbT      = (_Float16*)(ws + (size_t)MAXPOS * 8 + 4096);  // 1.5 MB
    float* x  = (float*)(ws + (size_t)MAXPOS * 8 + 4096 + (size_t)NPAD * D_ * 2);
    float* y1 = x + (size_t)B_ * XDIM;        // 256*1024
    float* y2 = y1 + (size_t)B_ * 1024;       // 256*512
    float* y3 = y2 + (size_t)B_ * 512;        // 256*256
    float* y4 = y3 + (size_t)B_ * 256;        // 256*30
    size_t ybytes = ((size_t)B_ * (1024 + 512 + 256 + 30)) * 4;

    hipMemsetAsync(y1, 0, ybytes, stream);    // split-K accumulators
    scan_kernel<<<1, 256, 0, stream>>>(spans, meta);
    pos_fill<<<B_, 256, 0, stream>>>(meta, pos_list);
    transpose_w<<<dim3(D_ / 32, NPAD / 32), 256, 0, stream>>>(aw1, WbT);
    attn_gemm_v2<<<MAXPOS / 32, 256, 0, stream>>>(
        embeds, WbT, ab1, aw2, pos_list, meta, attns);
    build_x<<<dim3(B_, 3), 256, 0, stream>>>(embeds, attns, meta, width_emb, x);

    mlp_gemm_sk<<<dim3(4, 16, 8), 256, 0, stream>>>(x,  sw1, y1, B_, 1024, XDIM, 292);
    bias_act<<<256, 256, 0, stream>>>(y1, sb1, y1, B_ * 1024, 1024, 1);
    mlp_gemm_sk<<<dim3(4, 8, 8), 256, 0, stream>>>(y1, sw2, y2, B_, 512, 1024, 128);
    bias_act<<<128, 256, 0, stream>>>(y2, sb2, y2, B_ * 512, 512, 1);
    mlp_gemm_sk<<<dim3(4, 4, 8), 256, 0, stream>>>(y2, sw3, y3, B_, 256, 512, 64);
    bias_act<<<64, 256, 0, stream>>>(y3, sb3, y3, B_ * 256, 256, 1);
    mlp_gemm_sk<<<dim3(4, 1, 8), 256, 0, stream>>>(y3, sw4, y4, B_, 30, 256, 32);
    bias_act<<<30, 256, 0, stream>>>(y4, sb4, out, B_ * 30, 30, 0);
}